// Round 1
// baseline (491.241 us; speedup 1.0000x reference)
//
#include <hip/hip_runtime.h>

#define NEG_INF (-__builtin_huge_valf())

// Max-plus 5x5 dilation, fp32, NCHW (16,64,256,256), 'same' pad (2,2) with -inf.
// Each thread: 4 output rows x 8 output cols. Block (32,8) covers 256x32 tile.
__global__ __launch_bounds__(256)
void semiconv2d_dilate(const float* __restrict__ in,
                       const float* __restrict__ ker,
                       float* __restrict__ out) {
    const int tx = threadIdx.x;          // 0..31 -> col group (8 cols each)
    const int ty = threadIdx.y;          // 0..7  -> row group (4 rows each)
    const int c  = tx << 3;              // base output col, 0..248
    const int r0 = (blockIdx.x << 5) + (ty << 2);   // base output row
    const long long plane = blockIdx.y;  // b*64 + ch, 0..1023

    const float* __restrict__ pin  = in  + plane * 65536;
    float* __restrict__       pout = out + plane * 65536;

    // 5x5 kernel into registers (uniform address; L1/scalar cached)
    float kk[25];
    #pragma unroll
    for (int t = 0; t < 25; ++t) kk[t] = ker[t];

    float acc[4][8];
    #pragma unroll
    for (int i = 0; i < 4; ++i)
        #pragma unroll
        for (int x = 0; x < 8; ++x) acc[i][x] = NEG_INF;

    // Input rows r0-2 .. r0+5 feed output rows r0 .. r0+3.
    #pragma unroll
    for (int ro = 0; ro < 8; ++ro) {
        const int ir = r0 - 2 + ro;
        // w[j] = input[ir][c - 4 + j], j in [0,16). Used entries: w[2..13].
        float w[16];
        if (ir >= 0 && ir < 256) {
            const float* rp = pin + (ir << 8) + c;
            if (tx > 0) {                 // cols c-4..c-1
                float4 a = *reinterpret_cast<const float4*>(rp - 4);
                w[0]=a.x; w[1]=a.y; w[2]=a.z; w[3]=a.w;
            } else { w[0]=NEG_INF; w[1]=NEG_INF; w[2]=NEG_INF; w[3]=NEG_INF; }
            float4 b = *reinterpret_cast<const float4*>(rp);       // c..c+3
            w[4]=b.x; w[5]=b.y; w[6]=b.z; w[7]=b.w;
            float4 d = *reinterpret_cast<const float4*>(rp + 4);   // c+4..c+7
            w[8]=d.x; w[9]=d.y; w[10]=d.z; w[11]=d.w;
            if (tx < 31) {                // cols c+8..c+11
                float4 e = *reinterpret_cast<const float4*>(rp + 8);
                w[12]=e.x; w[13]=e.y; w[14]=e.z; w[15]=e.w;
            } else { w[12]=NEG_INF; w[13]=NEG_INF; w[14]=NEG_INF; w[15]=NEG_INF; }
        } else {
            #pragma unroll
            for (int t = 0; t < 16; ++t) w[t] = NEG_INF;
        }

        // Input row ir contributes tap u = ro - i to output row i (if 0<=u<5).
        #pragma unroll
        for (int i = 0; i < 4; ++i) {
            const int u = ro - i;
            if (u >= 0 && u < 5) {        // folds at compile time (unrolled)
                #pragma unroll
                for (int v = 0; v < 5; ++v) {
                    const float kv = kk[u * 5 + v];
                    #pragma unroll
                    for (int x = 0; x < 8; ++x)
                        acc[i][x] = fmaxf(acc[i][x], w[x + v + 2] + kv);
                }
            }
        }
    }

    #pragma unroll
    for (int i = 0; i < 4; ++i) {
        float* op = pout + ((r0 + i) << 8) + c;
        *reinterpret_cast<float4*>(op)     = make_float4(acc[i][0], acc[i][1], acc[i][2], acc[i][3]);
        *reinterpret_cast<float4*>(op + 4) = make_float4(acc[i][4], acc[i][5], acc[i][6], acc[i][7]);
    }
}

extern "C" void kernel_launch(void* const* d_in, const int* in_sizes, int n_in,
                              void* d_out, int out_size, void* d_ws, size_t ws_size,
                              hipStream_t stream) {
    const float* in  = (const float*)d_in[0];   // (16,64,256,256) fp32
    const float* ker = (const float*)d_in[1];   // (5,5) fp32
    float* out = (float*)d_out;

    // 1024 planes of 256x256; each block does a 256-wide x 32-tall tile.
    dim3 grid(256 / 32, 16 * 64);
    dim3 block(32, 8);
    semiconv2d_dilate<<<grid, block, 0, stream>>>(in, ker, out);
}